// Round 2
// baseline (153.525 us; speedup 1.0000x reference)
//
#include <hip/hip_runtime.h>

// MultiHeadAttention — fused per-token head-mixing attention.
// B=32, S=2048 -> 65536 tokens; E=128; HEADS=32; HEAD_DIM=4.
// out[t] = softmax_over_kh( Q(t)K(t)^T * 0.5 ) V(t)  @ Wo^T + bo, with
// Q/K/V = x[t] @ W{q,k,v}^T reshaped (32 heads x 4 dims).
//
// R2 (fixes R1 compile): bf16 MFMA path kept verbatim from the 82.5us
// baseline; only storage + phase 2 change:
//  - Q/K/V in LDS as f16 (half the bytes of the old fp32), V transposed [d][kh]
//  - phase 2 token-stationary: 8 threads/token, 2 q-heads per pass share every
//    K/V ds_read_b128; v_dot2_f32_f16 halves the FMA count
//  - LDS 59392 -> 34816 B, __launch_bounds__(256,4): 4 blocks/CU (was 2)
//  - all half types are __fp16 ext-vectors (the builtins' native type)

#define TOKENS (32 * 2048)
#define E 128
#define NH 32
#define BT 32           // tokens per block
#define THREADS 256     // 4 waves
#define LPITCH 136      // f16 elems per LDS token row (272 B)

typedef __attribute__((ext_vector_type(8))) short short8;
typedef __attribute__((ext_vector_type(4))) float f32x4;
typedef __fp16 h2_t __attribute__((ext_vector_type(2)));

#if __has_builtin(__builtin_amdgcn_exp2f)
#define EXP2F __builtin_amdgcn_exp2f
#else
#define EXP2F exp2f
#endif

#if __has_builtin(__builtin_amdgcn_rcpf)
#define RCPF __builtin_amdgcn_rcpf
#else
#define RCPF(x) (1.0f / (x))
#endif

static __device__ __forceinline__ unsigned short f2bf(float f) {
    // round-to-nearest-even float -> bf16 bits
    unsigned u = __float_as_uint(f);
    unsigned r = (u + 0x7fffu + ((u >> 16) & 1u)) >> 16;
    return (unsigned short)r;
}

static __device__ __forceinline__ unsigned pk16(float a, float b) {
    return __builtin_bit_cast(unsigned, __builtin_amdgcn_cvt_pkrtz(a, b));
}
static __device__ __forceinline__ h2_t u2h(unsigned u) {
    return __builtin_bit_cast(h2_t, u);
}

// a.x*b.x + a.y*b.y + c  (v_dot2_f32_f16 when available)
static __device__ __forceinline__ float fdot2(h2_t a, h2_t b, float c) {
#if __has_builtin(__builtin_amdgcn_fdot2)
    return __builtin_amdgcn_fdot2(a, b, c, false);
#else
    return (float)a.x * (float)b.x + (float)a.y * (float)b.y + c;
#endif
}

// ---------------------------------------------------------------------------
// Prelude: pack Wq,Wk,Wv,Wo (fp32, [out=128][in=128]) into bf16 MFMA B-fragment
// order: wpk[proj][nt(8)][ks(4)][lane(64)][j(8)], where for lane l (c=l&15,
// g=l>>4): elem j = W[nt*16+c][ks*32 + g*8 + j].  (kappa(g,j)=g*8+j used for
// BOTH A and B fragments — valid since MFMA pairs A(g,j) with B(g,j).)
// ---------------------------------------------------------------------------
__global__ void pack_w(const float* __restrict__ Wq, const float* __restrict__ Wk,
                       const float* __restrict__ Wv, const float* __restrict__ Wo,
                       unsigned short* __restrict__ wpk) {
    int idx = blockIdx.x * blockDim.x + threadIdx.x;   // 4*8*4*64 = 8192
    if (idx >= 4 * 8 * 4 * 64) return;
    int lane = idx & 63;
    int ks   = (idx >> 6) & 3;
    int nt   = (idx >> 8) & 7;
    int proj = idx >> 11;
    const float* W = (proj == 0) ? Wq : (proj == 1) ? Wk : (proj == 2) ? Wv : Wo;
    int c = lane & 15, g = lane >> 4;
    const float* src = W + (size_t)(nt * 16 + c) * E + ks * 32 + g * 8;
    unsigned short* dst = wpk + (size_t)idx * 8;
#pragma unroll
    for (int j = 0; j < 8; ++j) dst[j] = f2bf(src[j]);
}

// ---------------------------------------------------------------------------
// Main fused kernel: 32 tokens per block, 4 waves, 4 blocks/CU.
// ---------------------------------------------------------------------------
__global__ __launch_bounds__(THREADS, 4) void mha_fused(
        const float* __restrict__ x, const unsigned short* __restrict__ wpk,
        const float* __restrict__ bo, float* __restrict__ out) {
    __shared__ __fp16 qs [BT * LPITCH];          // Q rows  [tok][qh*4+d]  f16
    __shared__ __fp16 ksh[BT * LPITCH];          // K rows  [tok][kh*4+d]  f16
    __shared__ __fp16 vth[BT * LPITCH];          // V^T     [tok][d*32+kh] f16
    __shared__ unsigned short at_[BT * LPITCH];  // attended [tok][qh*4+d] bf16

    const int tid  = threadIdx.x;
    const int wave = tid >> 6;
    const int lane = tid & 63;
    const int c = lane & 15, g = lane >> 4;
    const int bt0 = blockIdx.x * BT;

    // ---------------- Phase 1: Q,K,V projections (fused N=384) -------------
    {
        const int tt  = wave & 1;     // token tile (16 rows)
        const int nch = wave >> 1;    // column half: nc = nch*12 .. nch*12+11

        // A fragments: X rows in bf16, kappa(g,j)=g*8+j, reused over all nc
        short8 afrag[4];
        const float* xrow = x + (size_t)(bt0 + tt * 16 + c) * E;
#pragma unroll
        for (int ks2 = 0; ks2 < 4; ++ks2) {
            const float* p = xrow + ks2 * 32 + g * 8;
            float4 v0 = *(const float4*)(p);
            float4 v1 = *(const float4*)(p + 4);
            short8 a;
            a[0] = f2bf(v0.x); a[1] = f2bf(v0.y); a[2] = f2bf(v0.z); a[3] = f2bf(v0.w);
            a[4] = f2bf(v1.x); a[5] = f2bf(v1.y); a[6] = f2bf(v1.z); a[7] = f2bf(v1.w);
            afrag[ks2] = a;
        }

#pragma unroll
        for (int i = 0; i < 12; ++i) {
            int nc   = nch * 12 + i;      // 0..23 : [Q 0-7 | K 8-15 | V 16-23]
            int proj = nc >> 3;
            int nt   = nc & 7;
            const unsigned short* wb = wpk + ((size_t)((proj * 8 + nt) * 4) * 64 + lane) * 8;
            f32x4 acc = {0.f, 0.f, 0.f, 0.f};
#pragma unroll
            for (int ks2 = 0; ks2 < 4; ++ks2) {
                short8 b = *(const short8*)(wb + (size_t)ks2 * 64 * 8);
                acc = __builtin_amdgcn_mfma_f32_16x16x32_bf16(afrag[ks2], b, acc, 0, 0, 0);
            }
            int col = nt * 16 + c;
            if (proj < 2) {
                __fp16* dst = proj ? ksh : qs;
#pragma unroll
                for (int r2 = 0; r2 < 4; ++r2) {
                    int row = tt * 16 + g * 4 + r2;   // C/D: row=(l>>4)*4+reg, col=l&15
                    dst[row * LPITCH + col] = (__fp16)acc[r2];
                }
            } else {
                int vc = (col & 3) * 32 + (col >> 2);  // transpose: [d][kh]
#pragma unroll
                for (int r2 = 0; r2 < 4; ++r2) {
                    int row = tt * 16 + g * 4 + r2;
                    vth[row * LPITCH + vc] = (__fp16)acc[r2];
                }
            }
        }
    }
    __syncthreads();

    // ---------------- Phase 2: per-token attention, token-stationary -------
    // 8 threads per token (tok = tid>>3). Each pass handles TWO q-heads so
    // every K/V LDS read is shared. K/V reads: 8 distinct bcast addrs/wave,
    // 272B token pitch => the 8 16B slots tile all 32 banks (conflict-free).
    {
        const float cexp = 0.5f * 1.44269504088896340736f; // scale * log2(e)
        const int tok = tid >> 3;
        const int qb  = tid & 7;
        const __fp16* krow = ksh + tok * LPITCH;
        const __fp16* vrow = vth + tok * LPITCH;
        const __fp16* qrow = qs  + tok * LPITCH;
#pragma unroll 1
        for (int hlf = 0; hlf < 2; ++hlf) {
            const int qhA = qb + hlf * 8;   // 0..15
            const int qhB = qhA + 16;       // 16..31
            uint2 qrA = *(const uint2*)(qrow + qhA * 4);
            uint2 qrB = *(const uint2*)(qrow + qhB * 4);
            h2_t qA0 = u2h(qrA.x), qA1 = u2h(qrA.y);
            h2_t qB0 = u2h(qrB.x), qB1 = u2h(qrB.y);
            float sumA = 0.f, sumB = 0.f;
            unsigned pkA[16], pkB[16];      // exp(scores) packed f16 pairs
#pragma unroll
            for (int kp = 0; kp < 16; ++kp) {
                uint4 kr = *(const uint4*)(krow + kp * 8);  // kh = 2kp, 2kp+1
                float sA0 = fdot2(u2h(kr.x), qA0, fdot2(u2h(kr.y), qA1, 0.f));
                float sA1 = fdot2(u2h(kr.z), qA0, fdot2(u2h(kr.w), qA1, 0.f));
                float sB0 = fdot2(u2h(kr.x), qB0, fdot2(u2h(kr.y), qB1, 0.f));
                float sB1 = fdot2(u2h(kr.z), qB0, fdot2(u2h(kr.w), qB1, 0.f));
                float eA0 = EXP2F(sA0 * cexp), eA1 = EXP2F(sA1 * cexp);
                float eB0 = EXP2F(sB0 * cexp), eB1 = EXP2F(sB1 * cexp);
                sumA += eA0 + eA1; sumB += eB0 + eB1;
                pkA[kp] = pk16(eA0, eA1);
                pkB[kp] = pk16(eB0, eB1);
            }
            float aA[4], aB[4];
#pragma unroll
            for (int d = 0; d < 4; ++d) {
                float accA = 0.f, accB = 0.f;
#pragma unroll
                for (int vp = 0; vp < 4; ++vp) {
                    uint4 vr = *(const uint4*)(vrow + d * 32 + vp * 8); // kh pairs
                    accA = fdot2(u2h(pkA[vp * 4 + 0]), u2h(vr.x), accA);
                    accA = fdot2(u2h(pkA[vp * 4 + 1]), u2h(vr.y), accA);
                    accA = fdot2(u2h(pkA[vp * 4 + 2]), u2h(vr.z), accA);
                    accA = fdot2(u2h(pkA[vp * 4 + 3]), u2h(vr.w), accA);
                    accB = fdot2(u2h(pkB[vp * 4 + 0]), u2h(vr.x), accB);
                    accB = fdot2(u2h(pkB[vp * 4 + 1]), u2h(vr.y), accB);
                    accB = fdot2(u2h(pkB[vp * 4 + 2]), u2h(vr.z), accB);
                    accB = fdot2(u2h(pkB[vp * 4 + 3]), u2h(vr.w), accB);
                }
                aA[d] = accA; aB[d] = accB;
            }
            float rA = RCPF(sumA), rB = RCPF(sumB);
            unsigned short* atr = at_ + tok * LPITCH;
            uint2 stA, stB;
            stA.x = (unsigned)f2bf(aA[0] * rA) | ((unsigned)f2bf(aA[1] * rA) << 16);
            stA.y = (unsigned)f2bf(aA[2] * rA) | ((unsigned)f2bf(aA[3] * rA) << 16);
            stB.x = (unsigned)f2bf(aB[0] * rB) | ((unsigned)f2bf(aB[1] * rB) << 16);
            stB.y = (unsigned)f2bf(aB[2] * rB) | ((unsigned)f2bf(aB[3] * rB) << 16);
            *(uint2*)(atr + qhA * 4) = stA;
            *(uint2*)(atr + qhB * 4) = stB;
        }
    }
    __syncthreads();

    // ---------------- Phase 3: output projection + bias --------------------
    {
        const int tt  = wave & 1;
        const int ntg = wave >> 1;
        short8 af[4];
#pragma unroll
        for (int ks2 = 0; ks2 < 4; ++ks2) {
            af[ks2] = *(const short8*)(at_ + (tt * 16 + c) * LPITCH + ks2 * 32 + g * 8);
        }
#pragma unroll
        for (int i = 0; i < 4; ++i) {
            int nt = ntg * 4 + i;
            const unsigned short* wb = wpk + ((size_t)((3 * 8 + nt) * 4) * 64 + lane) * 8;
            f32x4 acc = {0.f, 0.f, 0.f, 0.f};
#pragma unroll
            for (int ks2 = 0; ks2 < 4; ++ks2) {
                short8 b = *(const short8*)(wb + (size_t)ks2 * 64 * 8);
                acc = __builtin_amdgcn_mfma_f32_16x16x32_bf16(af[ks2], b, acc, 0, 0, 0);
            }
            int col = nt * 16 + c;
            float bias = bo[col];
            float* orow = out + (size_t)(bt0 + tt * 16 + g * 4) * E + col;
#pragma unroll
            for (int r2 = 0; r2 < 4; ++r2) {
                orow[(size_t)r2 * E] = acc[r2] + bias;
            }
        }
    }
}

// ---------------------------------------------------------------------------
extern "C" void kernel_launch(void* const* d_in, const int* in_sizes, int n_in,
                              void* d_out, int out_size, void* d_ws, size_t ws_size,
                              hipStream_t stream) {
    const float* x  = (const float*)d_in[0];
    const float* Wq = (const float*)d_in[1];
    const float* Wk = (const float*)d_in[2];
    const float* Wv = (const float*)d_in[3];
    const float* Wo = (const float*)d_in[4];
    const float* bo = (const float*)d_in[5];
    unsigned short* wpk = (unsigned short*)d_ws;   // 4*8*4*64*8 bf16 = 128 KiB
    float* out = (float*)d_out;

    pack_w<<<32, 256, 0, stream>>>(Wq, Wk, Wv, Wo, wpk);
    mha_fused<<<TOKENS / BT, THREADS, 0, stream>>>(x, wpk, bo, out);
}

// Round 3
// 49.957 us; speedup vs baseline: 3.0731x; 3.0731x over previous
//
#include <hip/hip_runtime.h>

// MultiHeadAttention — fused per-token head-mixing attention.
// B=32, S=2048 -> 65536 tokens; E=128; HEADS=32; HEAD_DIM=4.
// out[t] = softmax_over_kh( Q(t)K(t)^T * 0.5 ) V(t)  @ Wo^T + bo, with
// Q/K/V = x[t] @ W{q,k,v}^T reshaped (32 heads x 4 dims).
//
// R3: identical to R2 except __launch_bounds__(256) — R2's (256,4) forced
// VGPR=64 and spilled phase-2's pk arrays to scratch (FETCH 17->200MB,
// WRITE 32->315MB, 153us). Structure retained:
//  - Q/K/V in LDS as f16 (half the bytes of fp32), V transposed [d][kh]
//  - phase 2 token-stationary: 8 threads/token, 2 q-heads per pass share every
//    K/V ds_read_b128; v_dot2_f32_f16 halves the FMA count
//  - LDS 34816 B -> up to 4 blocks/CU by LDS

#define TOKENS (32 * 2048)
#define E 128
#define NH 32
#define BT 32           // tokens per block
#define THREADS 256     // 4 waves
#define LPITCH 136      // f16 elems per LDS token row (272 B)

typedef __attribute__((ext_vector_type(8))) short short8;
typedef __attribute__((ext_vector_type(4))) float f32x4;
typedef __fp16 h2_t __attribute__((ext_vector_type(2)));

#if __has_builtin(__builtin_amdgcn_exp2f)
#define EXP2F __builtin_amdgcn_exp2f
#else
#define EXP2F exp2f
#endif

#if __has_builtin(__builtin_amdgcn_rcpf)
#define RCPF __builtin_amdgcn_rcpf
#else
#define RCPF(x) (1.0f / (x))
#endif

static __device__ __forceinline__ unsigned short f2bf(float f) {
    // round-to-nearest-even float -> bf16 bits
    unsigned u = __float_as_uint(f);
    unsigned r = (u + 0x7fffu + ((u >> 16) & 1u)) >> 16;
    return (unsigned short)r;
}

static __device__ __forceinline__ unsigned pk16(float a, float b) {
    return __builtin_bit_cast(unsigned, __builtin_amdgcn_cvt_pkrtz(a, b));
}
static __device__ __forceinline__ h2_t u2h(unsigned u) {
    return __builtin_bit_cast(h2_t, u);
}

// a.x*b.x + a.y*b.y + c  (v_dot2_f32_f16 when available)
static __device__ __forceinline__ float fdot2(h2_t a, h2_t b, float c) {
#if __has_builtin(__builtin_amdgcn_fdot2)
    return __builtin_amdgcn_fdot2(a, b, c, false);
#else
    return (float)a.x * (float)b.x + (float)a.y * (float)b.y + c;
#endif
}

// ---------------------------------------------------------------------------
// Prelude: pack Wq,Wk,Wv,Wo (fp32, [out=128][in=128]) into bf16 MFMA B-fragment
// order: wpk[proj][nt(8)][ks(4)][lane(64)][j(8)], where for lane l (c=l&15,
// g=l>>4): elem j = W[nt*16+c][ks*32 + g*8 + j].  (kappa(g,j)=g*8+j used for
// BOTH A and B fragments — valid since MFMA pairs A(g,j) with B(g,j).)
// ---------------------------------------------------------------------------
__global__ void pack_w(const float* __restrict__ Wq, const float* __restrict__ Wk,
                       const float* __restrict__ Wv, const float* __restrict__ Wo,
                       unsigned short* __restrict__ wpk) {
    int idx = blockIdx.x * blockDim.x + threadIdx.x;   // 4*8*4*64 = 8192
    if (idx >= 4 * 8 * 4 * 64) return;
    int lane = idx & 63;
    int ks   = (idx >> 6) & 3;
    int nt   = (idx >> 8) & 7;
    int proj = idx >> 11;
    const float* W = (proj == 0) ? Wq : (proj == 1) ? Wk : (proj == 2) ? Wv : Wo;
    int c = lane & 15, g = lane >> 4;
    const float* src = W + (size_t)(nt * 16 + c) * E + ks * 32 + g * 8;
    unsigned short* dst = wpk + (size_t)idx * 8;
#pragma unroll
    for (int j = 0; j < 8; ++j) dst[j] = f2bf(src[j]);
}

// ---------------------------------------------------------------------------
// Main fused kernel: 32 tokens per block, 4 waves.
// ---------------------------------------------------------------------------
__global__ __launch_bounds__(THREADS) void mha_fused(
        const float* __restrict__ x, const unsigned short* __restrict__ wpk,
        const float* __restrict__ bo, float* __restrict__ out) {
    __shared__ __fp16 qs [BT * LPITCH];          // Q rows  [tok][qh*4+d]  f16
    __shared__ __fp16 ksh[BT * LPITCH];          // K rows  [tok][kh*4+d]  f16
    __shared__ __fp16 vth[BT * LPITCH];          // V^T     [tok][d*32+kh] f16
    __shared__ unsigned short at_[BT * LPITCH];  // attended [tok][qh*4+d] bf16

    const int tid  = threadIdx.x;
    const int wave = tid >> 6;
    const int lane = tid & 63;
    const int c = lane & 15, g = lane >> 4;
    const int bt0 = blockIdx.x * BT;

    // ---------------- Phase 1: Q,K,V projections (fused N=384) -------------
    {
        const int tt  = wave & 1;     // token tile (16 rows)
        const int nch = wave >> 1;    // column half: nc = nch*12 .. nch*12+11

        // A fragments: X rows in bf16, kappa(g,j)=g*8+j, reused over all nc
        short8 afrag[4];
        const float* xrow = x + (size_t)(bt0 + tt * 16 + c) * E;
#pragma unroll
        for (int ks2 = 0; ks2 < 4; ++ks2) {
            const float* p = xrow + ks2 * 32 + g * 8;
            float4 v0 = *(const float4*)(p);
            float4 v1 = *(const float4*)(p + 4);
            short8 a;
            a[0] = f2bf(v0.x); a[1] = f2bf(v0.y); a[2] = f2bf(v0.z); a[3] = f2bf(v0.w);
            a[4] = f2bf(v1.x); a[5] = f2bf(v1.y); a[6] = f2bf(v1.z); a[7] = f2bf(v1.w);
            afrag[ks2] = a;
        }

#pragma unroll
        for (int i = 0; i < 12; ++i) {
            int nc   = nch * 12 + i;      // 0..23 : [Q 0-7 | K 8-15 | V 16-23]
            int proj = nc >> 3;
            int nt   = nc & 7;
            const unsigned short* wb = wpk + ((size_t)((proj * 8 + nt) * 4) * 64 + lane) * 8;
            f32x4 acc = {0.f, 0.f, 0.f, 0.f};
#pragma unroll
            for (int ks2 = 0; ks2 < 4; ++ks2) {
                short8 b = *(const short8*)(wb + (size_t)ks2 * 64 * 8);
                acc = __builtin_amdgcn_mfma_f32_16x16x32_bf16(afrag[ks2], b, acc, 0, 0, 0);
            }
            int col = nt * 16 + c;
            if (proj < 2) {
                __fp16* dst = proj ? ksh : qs;
#pragma unroll
                for (int r2 = 0; r2 < 4; ++r2) {
                    int row = tt * 16 + g * 4 + r2;   // C/D: row=(l>>4)*4+reg, col=l&15
                    dst[row * LPITCH + col] = (__fp16)acc[r2];
                }
            } else {
                int vc = (col & 3) * 32 + (col >> 2);  // transpose: [d][kh]
#pragma unroll
                for (int r2 = 0; r2 < 4; ++r2) {
                    int row = tt * 16 + g * 4 + r2;
                    vth[row * LPITCH + vc] = (__fp16)acc[r2];
                }
            }
        }
    }
    __syncthreads();

    // ---------------- Phase 2: per-token attention, token-stationary -------
    // 8 threads per token (tok = tid>>3). Each pass handles TWO q-heads so
    // every K/V LDS read is shared. K/V reads: 8 distinct bcast addrs/wave,
    // 272B token pitch => the 8 16B slots tile all 32 banks (conflict-free).
    {
        const float cexp = 0.5f * 1.44269504088896340736f; // scale * log2(e)
        const int tok = tid >> 3;
        const int qb  = tid & 7;
        const __fp16* krow = ksh + tok * LPITCH;
        const __fp16* vrow = vth + tok * LPITCH;
        const __fp16* qrow = qs  + tok * LPITCH;
#pragma unroll 1
        for (int hlf = 0; hlf < 2; ++hlf) {
            const int qhA = qb + hlf * 8;   // 0..15
            const int qhB = qhA + 16;       // 16..31
            uint2 qrA = *(const uint2*)(qrow + qhA * 4);
            uint2 qrB = *(const uint2*)(qrow + qhB * 4);
            h2_t qA0 = u2h(qrA.x), qA1 = u2h(qrA.y);
            h2_t qB0 = u2h(qrB.x), qB1 = u2h(qrB.y);
            float sumA = 0.f, sumB = 0.f;
            unsigned pkA[16], pkB[16];      // exp(scores) packed f16 pairs
#pragma unroll
            for (int kp = 0; kp < 16; ++kp) {
                uint4 kr = *(const uint4*)(krow + kp * 8);  // kh = 2kp, 2kp+1
                float sA0 = fdot2(u2h(kr.x), qA0, fdot2(u2h(kr.y), qA1, 0.f));
                float sA1 = fdot2(u2h(kr.z), qA0, fdot2(u2h(kr.w), qA1, 0.f));
                float sB0 = fdot2(u2h(kr.x), qB0, fdot2(u2h(kr.y), qB1, 0.f));
                float sB1 = fdot2(u2h(kr.z), qB0, fdot2(u2h(kr.w), qB1, 0.f));
                float eA0 = EXP2F(sA0 * cexp), eA1 = EXP2F(sA1 * cexp);
                float eB0 = EXP2F(sB0 * cexp), eB1 = EXP2F(sB1 * cexp);
                sumA += eA0 + eA1; sumB += eB0 + eB1;
                pkA[kp] = pk16(eA0, eA1);
                pkB[kp] = pk16(eB0, eB1);
            }
            float aA[4], aB[4];
#pragma unroll
            for (int d = 0; d < 4; ++d) {
                float accA = 0.f, accB = 0.f;
#pragma unroll
                for (int vp = 0; vp < 4; ++vp) {
                    uint4 vr = *(const uint4*)(vrow + d * 32 + vp * 8); // kh pairs
                    accA = fdot2(u2h(pkA[vp * 4 + 0]), u2h(vr.x), accA);
                    accA = fdot2(u2h(pkA[vp * 4 + 1]), u2h(vr.y), accA);
                    accA = fdot2(u2h(pkA[vp * 4 + 2]), u2h(vr.z), accA);
                    accA = fdot2(u2h(pkA[vp * 4 + 3]), u2h(vr.w), accA);
                    accB = fdot2(u2h(pkB[vp * 4 + 0]), u2h(vr.x), accB);
                    accB = fdot2(u2h(pkB[vp * 4 + 1]), u2h(vr.y), accB);
                    accB = fdot2(u2h(pkB[vp * 4 + 2]), u2h(vr.z), accB);
                    accB = fdot2(u2h(pkB[vp * 4 + 3]), u2h(vr.w), accB);
                }
                aA[d] = accA; aB[d] = accB;
            }
            float rA = RCPF(sumA), rB = RCPF(sumB);
            unsigned short* atr = at_ + tok * LPITCH;
            uint2 stA, stB;
            stA.x = (unsigned)f2bf(aA[0] * rA) | ((unsigned)f2bf(aA[1] * rA) << 16);
            stA.y = (unsigned)f2bf(aA[2] * rA) | ((unsigned)f2bf(aA[3] * rA) << 16);
            stB.x = (unsigned)f2bf(aB[0] * rB) | ((unsigned)f2bf(aB[1] * rB) << 16);
            stB.y = (unsigned)f2bf(aB[2] * rB) | ((unsigned)f2bf(aB[3] * rB) << 16);
            *(uint2*)(atr + qhA * 4) = stA;
            *(uint2*)(atr + qhB * 4) = stB;
        }
    }
    __syncthreads();

    // ---------------- Phase 3: output projection + bias --------------------
    {
        const int tt  = wave & 1;
        const int ntg = wave >> 1;
        short8 af[4];
#pragma unroll
        for (int ks2 = 0; ks2 < 4; ++ks2) {
            af[ks2] = *(const short8*)(at_ + (tt * 16 + c) * LPITCH + ks2 * 32 + g * 8);
        }
#pragma unroll
        for (int i = 0; i < 4; ++i) {
            int nt = ntg * 4 + i;
            const unsigned short* wb = wpk + ((size_t)((3 * 8 + nt) * 4) * 64 + lane) * 8;
            f32x4 acc = {0.f, 0.f, 0.f, 0.f};
#pragma unroll
            for (int ks2 = 0; ks2 < 4; ++ks2) {
                short8 b = *(const short8*)(wb + (size_t)ks2 * 64 * 8);
                acc = __builtin_amdgcn_mfma_f32_16x16x32_bf16(af[ks2], b, acc, 0, 0, 0);
            }
            int col = nt * 16 + c;
            float bias = bo[col];
            float* orow = out + (size_t)(bt0 + tt * 16 + g * 4) * E + col;
#pragma unroll
            for (int r2 = 0; r2 < 4; ++r2) {
                orow[(size_t)r2 * E] = acc[r2] + bias;
            }
        }
    }
}

// ---------------------------------------------------------------------------
extern "C" void kernel_launch(void* const* d_in, const int* in_sizes, int n_in,
                              void* d_out, int out_size, void* d_ws, size_t ws_size,
                              hipStream_t stream) {
    const float* x  = (const float*)d_in[0];
    const float* Wq = (const float*)d_in[1];
    const float* Wk = (const float*)d_in[2];
    const float* Wv = (const float*)d_in[3];
    const float* Wo = (const float*)d_in[4];
    const float* bo = (const float*)d_in[5];
    unsigned short* wpk = (unsigned short*)d_ws;   // 4*8*4*64*8 bf16 = 128 KiB
    float* out = (float*)d_out;

    pack_w<<<32, 256, 0, stream>>>(Wq, Wk, Wv, Wo, wpk);
    mha_fused<<<TOKENS / BT, THREADS, 0, stream>>>(x, wpk, bo, out);
}